// Round 1
// baseline (3533.520 us; speedup 1.0000x reference)
//
#include <hip/hip_runtime.h>
#include <math.h>

#define NB 16
#define NT 64
#define NQc 256
#define HD 64
#define PF 4

// ws layout (float offsets)
#define WS_W2M 0        // 64*192 = 12288
#define WS_CB  12288    // 192
#define WS_QE1 12480    // 256*64 = 16384
#define WS_XE1 28864    // 16*64*64 = 65536
#define WS_G   94400    // 256*256 = 65536
#define WS_HW  159936   // 16*65*256 = 266240
#define WS_FLAGS 426176 // 1024 uints (16b x 64t)

// ---------------- precompute kernel ----------------
__global__ __launch_bounds__(256) void kPrep(
    const int* __restrict__ q, const int* __restrict__ r,
    const float* __restrict__ x_emb, const float* __restrict__ q_emb,
    const float* __restrict__ init_h, const float* __restrict__ w1,
    const float* __restrict__ b1, const float* __restrict__ w2,
    const float* __restrict__ b2, const float* __restrict__ w_ih,
    const float* __restrict__ b_ih, float* __restrict__ ws,
    float* __restrict__ h_full)
{
  int idx = blockIdx.x*256 + threadIdx.x;
  if (idx < 12288) {
    // W2m[j][g] = sum_i w2[j][i] * w_ih[g][i]   (m-part cols of w_ih)
    int j = idx/192, g = idx%192;
    float s = 0.f;
    for (int i=0;i<64;i++) s += w2[j*64+i]*w_ih[g*128+i];
    ws[WS_W2M+idx] = s;
  } else if (idx < 12480) {
    // cb[g] = b_ih[g] + sum_i b2[i]*w_ih[g][i]
    int g = idx-12288;
    float s = b_ih[g];
    for (int i=0;i<64;i++) s += b2[i]*w_ih[g*128+i];
    ws[WS_CB+g] = s;
  } else if (idx < 28864) {
    // qe1[c][i] = b1[i] + sum_k q_emb[c][k]*w1[64+k][i]
    int e = idx-12480; int c = e>>6, i = e&63;
    float s = b1[i];
    for (int k=0;k<64;k++) s += q_emb[c*64+k]*w1[(64+k)*64+i];
    ws[WS_QE1+e] = s;
  } else if (idx < 94400) {
    // xe1[b*64+t][i] = b1[i] + sum_k x_emb[q+256r][k]*w1[64+k][i]
    int e = idx-28864; int bt = e>>6, i = e&63;
    int row = q[bt] + 256*r[bt];
    float s = b1[i];
    for (int k=0;k<64;k++) s += x_emb[row*64+k]*w1[(64+k)*64+i];
    ws[WS_XE1+e] = s;
  } else if (idx < 159936) {
    // Gram: G[a][cc] = q_emb[a] . q_emb[cc]
    int e = idx-94400; int a = e>>8, cc = e&255;
    float s = 0.f;
    for (int d=0;d<64;d++) s += q_emb[a*64+d]*q_emb[cc*64+d];
    ws[WS_G+e] = s;
  } else if (idx < 422080) {
    // h_full[b][0][c][f] = init_h[c][f]
    int e = idx-159936; int bb = e>>14, cf = e&16383;
    h_full[(size_t)bb*65*16384 + cf] = init_h[cf];
  }
}

// ---------------- wavefront recurrence kernel ----------------
// 256 WGs: bid = tg*16 + b  (b = bid&15, tg = bid>>4). WG handles t = tg+16j, j=0..3.
// Threads: tid<192 "g-threads" (one gate-output g each, weights in VGPRs),
//          tid>=192 "i-threads" (MLP hidden col i, w1h col in VGPRs).
__global__ __launch_bounds__(256,1) void kA(
    const int* __restrict__ q, const float* __restrict__ init_h,
    const float* __restrict__ w1, const float* __restrict__ w_ih,
    const float* __restrict__ w_hh, const float* __restrict__ b_hh,
    const float* __restrict__ ws, float* __restrict__ h_full,
    unsigned* __restrict__ flags)
{
  const int bid = blockIdx.x, b = bid & 15, tg = bid >> 4;
  const int tid = threadIdx.x;
  const bool isG = tid < 192;
  __shared__ float ring[8][64];
  __shared__ float hsh[64], ash[64], rgs[64], ngs[64];
  const float* W2m = ws + WS_W2M;
  const float* cbp = ws + WS_CB;
  const float* qe1 = ws + WS_QE1;
  const float* xe1 = ws + WS_XE1;

  float wA[64], wB[64], wC[64];
  float cbv = 0.f, bhhv = 0.f;
  if (isG) {
    const int g = tid;
    #pragma unroll
    for (int k=0;k<64;k++) wA[k] = w_ih[g*128+64+k];   // ht-part row of w_ih
    #pragma unroll
    for (int k=0;k<64;k++) wB[k] = W2m[k*192+g];       // W2m column g
    #pragma unroll
    for (int k=0;k<64;k++) wC[k] = w_hh[g*64+k];       // w_hh row g
    cbv = cbp[g]; bhhv = b_hh[g];
  } else {
    const int i = tid-192;
    #pragma unroll
    for (int k=0;k<64;k++) wA[k] = w1[k*64+i];         // w1h column i
  }

  for (int j=0;j<4;j++) {
    const int t = tg + 16*j;
    __syncthreads();  // protect hsh/ring reuse across passes
    const int qrow = q[b*64+t];
    float xv = 0.f, qv = 0.f;
    if (!isG) {
      xv = xe1[(b*64+t)*64 + (tid-192)];
      qv = qe1[tid-192];                       // row 0 prefetch
    }
    float* hf_cur  = h_full + (size_t)(b*65 + t + 1)*16384;
    float* hf_prev = h_full + (size_t)(b*65 + t)*16384;
    unsigned* flg_prev = flags + (b*64 + t - 1);
    unsigned* flg_cur  = flags + (b*64 + t);

    if (tid < 64) {
      hsh[tid] = 0.f;
      for (int rr=0; rr<PF; rr++) {
        if (t > 0) {
          while (__hip_atomic_load(flg_prev, __ATOMIC_ACQUIRE, __HIP_MEMORY_SCOPE_AGENT) < (unsigned)(rr+1))
            __builtin_amdgcn_s_sleep(2);
          ring[rr][tid] = __hip_atomic_load(hf_prev + rr*64 + tid, __ATOMIC_RELAXED, __HIP_MEMORY_SCOPE_AGENT);
        } else {
          ring[rr][tid] = init_h[rr*64+tid];
        }
      }
    }
    bool pend = false; int pr = 0; float rowreg = 0.f;
    __syncthreads();

    for (int c=0;c<256;c++) {
      const float* hr = ring[c & 7];
      // S1: dots vs previous-timestep row (g: wihH part of gi; i: MLP hidden)
      float acc1 = isG ? cbv : ((c==qrow) ? xv : qv);
      #pragma unroll
      for (int k=0;k<64;k++) acc1 += hr[k]*wA[k];
      if (!isG) ash[tid-192] = fmaxf(acc1, 0.f);
      __syncthreads();  // B_mid: ash ready, hsh (prev cell) stable
      // S2: g-threads: gh dot over recurrent h; gi += a . W2m
      float acc2 = acc1, acch = bhhv;
      if (isG) {
        #pragma unroll
        for (int k=0;k<64;k++) { acch += hsh[k]*wC[k]; acc2 += ash[k]*wB[k]; }
        if (tid < 64) rgs[tid] = 1.f/(1.f+__expf(-(acc2+acch)));   // reset gate
      }
      __syncthreads();  // B_rg: rgs ready
      if (tid >= 128 && isG) {   // candidate gate: tanh(i_n + rg*h_n)
        float x2 = acc2 + rgs[tid-128]*acch;
        float e2 = __expf(2.f*x2);
        ngs[tid-128] = 1.f - 2.f/(e2+1.f);
      }
      if (tid < 64) {
        // loader duties: commit pending row; fetch row c+PF
        if (pend) ring[pr & 7][tid] = rowreg;
        int nxt = c + PF;
        if (nxt < 256) {
          if (t > 0) {
            while (__hip_atomic_load(flg_prev, __ATOMIC_ACQUIRE, __HIP_MEMORY_SCOPE_AGENT) < (unsigned)(nxt+1))
              __builtin_amdgcn_s_sleep(2);
            rowreg = __hip_atomic_load(hf_prev + nxt*64 + tid, __ATOMIC_RELAXED, __HIP_MEMORY_SCOPE_AGENT);
          } else {
            rowreg = init_h[nxt*64+tid];
          }
          pr = nxt; pend = true;
        } else pend = false;
      }
      if (!isG) qv = (c < 255) ? qe1[(c+1)*64 + (tid-192)] : 0.f;  // prefetch next qe1 row
      __syncthreads();  // B_ng: ngs ready, ring commit done
      if (tid >= 64 && tid < 128) {  // update gate + state update + publish
        const int j3 = tid-64;
        float zv = 1.f/(1.f+__expf(-(acc2+acch)));
        float hn = zv*hsh[j3] + (1.f-zv)*ngs[j3];
        hsh[j3] = hn;
        __hip_atomic_store(hf_cur + c*64 + j3, hn, __ATOMIC_RELAXED, __HIP_MEMORY_SCOPE_AGENT);
        if (j3 == 0 && (c & 3) == 3)
          __hip_atomic_store(flg_cur, (unsigned)(c+1), __ATOMIC_RELEASE, __HIP_MEMORY_SCOPE_AGENT);
      }
    }
  }
}

// ---------------- hw[b][u][c] = h_full[b][u][c][:] . out_w ----------------
__global__ __launch_bounds__(256) void kHw(const float* __restrict__ h_full,
    const float* __restrict__ out_w, float* __restrict__ hw)
{
  __shared__ float ow[64];
  if (threadIdx.x < 64) ow[threadIdx.x] = out_w[threadIdx.x];
  __syncthreads();
  const int blk = blockIdx.x, c = threadIdx.x;
  const float* hp = h_full + ((size_t)blk*256 + c)*64;
  float s = 0.f;
  #pragma unroll
  for (int f=0;f<64;f++) s += hp[f]*ow[f];
  hw[blk*256+c] = s;
}

// ---------------- readout: softmax over history + logits ----------------
__global__ __launch_bounds__(256) void kY(const int* __restrict__ q,
    const float* __restrict__ ws, const float* __restrict__ bias,
    const float* __restrict__ theta, float* __restrict__ y)
{
  const float* G  = ws + WS_G;
  const float* hw = ws + WS_HW;
  const int b = blockIdx.x >> 2, tq = blockIdx.x & 3;
  const int c = threadIdx.x;
  __shared__ float siml[64][256];   // 64KB: sim[b][u][c] = G[q[b][u]][c]
  for (int u=0;u<64;u++) {
    int qq = q[b*64+u];
    siml[u][c] = G[qq*256+c];
  }
  __syncthreads();
  const float rate = __expf(theta[0]);
  const float bv = bias[c];
  const float* hwb = hw + b*65*256;
  for (int tt=0;tt<16;tt++) {
    const int t = tq*16+tt;
    float mx = -1e30f;
    for (int u=0;u<=t;u++) {
      float s = __expf(-rate*(float)(t-u))*siml[u][c];
      mx = fmaxf(mx, s);
    }
    float se = 0.f, sw = 0.f;
    for (int u=0;u<=t;u++) {
      float s = __expf(-rate*(float)(t-u))*siml[u][c];
      float e = __expf(s-mx);
      se += e; sw += e*hwb[u*256+c];
    }
    float lg = hwb[(t+1)*256+c] + sw/se + bv;
    y[(b*64+t)*256+c] = 1.f/(1.f+__expf(-lg));
  }
}

extern "C" void kernel_launch(void* const* d_in, const int* in_sizes, int n_in,
                              void* d_out, int out_size, void* d_ws, size_t ws_size,
                              hipStream_t stream)
{
  (void)in_sizes; (void)n_in; (void)out_size; (void)ws_size;
  const int*   q      = (const int*)  d_in[0];
  const int*   r      = (const int*)  d_in[1];
  const float* x_emb  = (const float*)d_in[2];
  const float* q_emb  = (const float*)d_in[3];
  const float* init_h = (const float*)d_in[4];
  const float* w1     = (const float*)d_in[5];
  const float* b1     = (const float*)d_in[6];
  const float* w2     = (const float*)d_in[7];
  const float* b2     = (const float*)d_in[8];
  const float* w_ih   = (const float*)d_in[9];
  const float* w_hh   = (const float*)d_in[10];
  const float* b_ih   = (const float*)d_in[11];
  const float* b_hh   = (const float*)d_in[12];
  const float* bias   = (const float*)d_in[13];
  const float* out_w  = (const float*)d_in[14];
  const float* theta  = (const float*)d_in[15];

  float* out    = (float*)d_out;
  float* y      = out;                 // (16,64,256)
  float* h_full = out + 262144;        // (16,65,256,64)
  float* ws     = (float*)d_ws;
  unsigned* flags = (unsigned*)(ws + WS_FLAGS);

  hipMemsetAsync(flags, 0, 1024*sizeof(unsigned), stream);
  kPrep<<<1649,256,0,stream>>>(q,r,x_emb,q_emb,init_h,w1,b1,w2,b2,w_ih,b_ih,ws,h_full);
  {
    void* ka[] = { (void*)&q, (void*)&init_h, (void*)&w1, (void*)&w_ih, (void*)&w_hh,
                   (void*)&b_hh, (void*)&ws, (void*)&h_full, (void*)&flags };
    hipError_t e = hipLaunchCooperativeKernel((const void*)kA, dim3(256), dim3(256), ka, 0, stream);
    if (e != hipSuccess) {
      // fallback: plain launch (256 WGs at this footprint co-schedule on 256 CUs)
      kA<<<dim3(256),dim3(256),0,stream>>>(q,init_h,w1,w_ih,w_hh,b_hh,ws,h_full,flags);
    }
  }
  kHw<<<1040,256,0,stream>>>(h_full, out_w, ws + WS_HW);
  kY<<<64,256,0,stream>>>(q, ws, bias, theta, y);
}

// Round 2
// 802.371 us; speedup vs baseline: 4.4038x; 4.4038x over previous
//
#include <hip/hip_runtime.h>
#include <math.h>

#define NB 16
#define NT 64
#define NQc 256
#define HD 64

// ---- ws layout (float-slot offsets) ----
#define WS_CB     0         // 192
#define WS_QE1    192       // 16384
#define WS_XE1    16576     // 65536
#define WS_G      82112     // 65536
#define WS_HW     147648    // 266240
#define WS_U16    413888    // 8192 u32 (U=[w1h;wihH] 256 rows x 32 half2)
#define WS_WHH16  422080    // 6144 u32 (w_hh 192 rows x 32 half2)
#define WS_W2M16  428224    // 6144 u32 (W2m^T 192 rows x 32 half2)
#define WS_I16    434368    // 8192 u32 (init_h 256 rows x 32 half2)
#define WS_GFLAG  442560    // 256 u32

typedef _Float16 h2 __attribute__((ext_vector_type(2)));

#if defined(__has_builtin)
#if __has_builtin(__builtin_amdgcn_fdot2)
#define FDOT2(a,b,c) __builtin_amdgcn_fdot2((a),(b),(c),false)
#endif
#endif
#ifndef FDOT2
__device__ inline float fdot2_sw(h2 a, h2 b, float c){ return c + (float)a[0]*(float)b[0] + (float)a[1]*(float)b[1]; }
#define FDOT2(a,b,c) fdot2_sw((a),(b),(c))
#endif

__device__ inline h2 H2(unsigned u){ union{unsigned x; h2 h;} v; v.x=u; return v.h; }
__device__ inline unsigned short F2H(float f){ union{_Float16 h; unsigned short s;} v; v.h=(_Float16)f; return v.s; }
__device__ inline unsigned PACK2(float a, float b){ return (unsigned)F2H(a) | ((unsigned)F2H(b)<<16); }

#define WGACQ(p)    __hip_atomic_load((p), __ATOMIC_ACQUIRE, __HIP_MEMORY_SCOPE_WORKGROUP)
#define WGREL(p,v)  __hip_atomic_store((p), (v), __ATOMIC_RELEASE, __HIP_MEMORY_SCOPE_WORKGROUP)
#define SPIN(p,tgt) while (WGACQ(p) < (tgt)) __builtin_amdgcn_s_sleep(1)

// ================= precompute =================
__global__ __launch_bounds__(256) void kPrep(
    const int* __restrict__ q, const int* __restrict__ r,
    const float* __restrict__ x_emb, const float* __restrict__ q_emb,
    const float* __restrict__ init_h, const float* __restrict__ w1,
    const float* __restrict__ b1, const float* __restrict__ w2,
    const float* __restrict__ b2, const float* __restrict__ w_ih,
    const float* __restrict__ w_hh, const float* __restrict__ b_ih,
    float* __restrict__ ws, float* __restrict__ h_full)
{
  int idx = blockIdx.x*256 + threadIdx.x;
  unsigned* wsu = (unsigned*)ws;
  if (idx < 192) {
    // cb[g] = b_ih[g] + sum_j b2[j]*w_ih[g][j]
    int g = idx; float s = b_ih[g];
    for (int j=0;j<64;j++) s += b2[j]*w_ih[g*128+j];
    ws[WS_CB+g] = s;
  } else if (idx < 16576) {
    // qe1[c][i] = b1[i] + sum_k q_emb[c][k]*w1[(64+k)*64+i]
    int e = idx-192; int c = e>>6, i = e&63;
    float s = b1[i];
    for (int k=0;k<64;k++) s += q_emb[c*64+k]*w1[(64+k)*64+i];
    ws[WS_QE1+e] = s;
  } else if (idx < 82112) {
    // xe1[b*64+t][i]
    int e = idx-16576; int bt = e>>6, i = e&63;
    int row = q[bt] + 256*r[bt];
    float s = b1[i];
    for (int k=0;k<64;k++) s += x_emb[row*64+k]*w1[(64+k)*64+i];
    ws[WS_XE1+e] = s;
  } else if (idx < 147648) {
    // Gram
    int e = idx-82112; int a = e>>8, cc = e&255;
    float s = 0.f;
    for (int d=0;d<64;d++) s += q_emb[a*64+d]*q_emb[cc*64+d];
    ws[WS_G+e] = s;
  } else if (idx < 409792) {
    // h_full[b][0] = init_h
    int e = idx-147648; int bb = e>>14, cf = e&16383;
    h_full[(size_t)bb*65*16384 + cf] = init_h[cf];
  } else if (idx < 417984) {
    // U16: row rr (0..255), pair d: U[rr][k] = rr<64 ? w1[k*64+rr] : w_ih[(rr-64)*128+64+k]
    int e = idx-409792; int rr = e>>5, d = e&31;
    float v0, v1;
    if (rr < 64) { v0 = w1[(2*d)*64+rr];   v1 = w1[(2*d+1)*64+rr]; }
    else { int g = rr-64; v0 = w_ih[g*128+64+2*d]; v1 = w_ih[g*128+64+2*d+1]; }
    wsu[WS_U16+e] = PACK2(v0,v1);
  } else if (idx < 424128) {
    // Whh16
    int e = idx-417984; int g = e>>5, d = e&31;
    wsu[WS_WHH16+e] = PACK2(w_hh[g*64+2*d], w_hh[g*64+2*d+1]);
  } else if (idx < 430272) {
    // W2m16[g][pair d]: W2m[a][g] = sum_j w2[a][j]*w_ih[g][j]   (a = 2d, 2d+1)
    int e = idx-424128; int g = e>>5, d = e&31;
    float s0=0.f, s1=0.f;
    for (int j=0;j<64;j++){ float wij = w_ih[g*128+j]; s0 += w2[(2*d)*64+j]*wij; s1 += w2[(2*d+1)*64+j]*wij; }
    wsu[WS_W2M16+e] = PACK2(s0,s1);
  } else if (idx < 438464) {
    // init_h f16
    int e = idx-430272; int c = e>>5, d = e&31;
    wsu[WS_I16+e] = PACK2(init_h[c*64+2*d], init_h[c*64+2*d+1]);
  }
}

// ================= wavefront recurrence =================
// 256 WGs x 512 threads. bid: b = bid&15, tg = bid>>4. Chains t = 4*tg + i, i=0..3.
// waves 0-3: "A" (GRU critical, per chain). waves 4-7: "B" (gi precompute + I/O).
__global__ __launch_bounds__(512,2) void kA(
    const int* __restrict__ q, const float* __restrict__ b_hh,
    float* __restrict__ ws, float* __restrict__ h_full)
{
  __shared__ __align__(16) unsigned short h16s[4][16][64];  // f16 h rings (per chain)
  __shared__ __align__(16) unsigned short inbox[16][64];    // chain-0 source rows
  __shared__ __align__(16) unsigned short a16s[4][8][64];   // relu(m1) f16 rings
  __shared__ float h32s[4][8][64];                          // f32 h rings (for copyout)
  __shared__ float gi3s[4][4][3][64];                       // gi parts f32
  __shared__ int flgH[4], flgB[4], flgC[4];

  const int bid = blockIdx.x;
  const int b = bid & 15, tg = bid >> 4;
  const int tid = threadIdx.x, w = tid>>6, lane = tid&63;
  const bool isA = (w < 4);
  const int i = isA ? w : (w-4);
  const int t = tg*4 + i;

  const unsigned* U16  = (const unsigned*)ws + WS_U16;
  const unsigned* WH16 = (const unsigned*)ws + WS_WHH16;
  const unsigned* WM16 = (const unsigned*)ws + WS_W2M16;
  const unsigned* I16  = (const unsigned*)ws + WS_I16;
  const float* qe1 = ws + WS_QE1;
  const float* xe1 = ws + WS_XE1;
  const float* cb  = ws + WS_CB;
  unsigned* gflag  = (unsigned*)ws + WS_GFLAG;
  unsigned* hfu    = (unsigned*)h_full;

  if (tid < 4) { flgH[tid]=0; flgB[tid]=0; flgC[tid]=0; }
  if (isA) h16s[i][15][lane] = 0;   // h(-1) = 0
  __syncthreads();

  if (isA) {
    // ---------------- A: GRU critical wave for chain i ----------------
    h2 wr[32], wz[32], wn[32], w2n[32];
    #pragma unroll
    for (int d=0; d<32; d++) {
      wr[d]  = H2(WH16[(lane)*32+d]);
      wz[d]  = H2(WH16[(64+lane)*32+d]);
      wn[d]  = H2(WH16[(128+lane)*32+d]);
      w2n[d] = H2(WM16[(128+lane)*32+d]);
    }
    const float bhr = b_hh[lane], bhz = b_hh[64+lane], bhn = b_hh[128+lane];
    float hreg = 0.f;

    SPIN(&flgB[i], 1);
    float gWn_cur = 0.f;
    {
      const uint4* ap = (const uint4*)a16s[i][0];
      #pragma unroll
      for (int k=0;k<8;k++){ uint4 c4 = ap[k];
        gWn_cur = FDOT2(w2n[4*k+0], H2(c4.x), gWn_cur);
        gWn_cur = FDOT2(w2n[4*k+1], H2(c4.y), gWn_cur);
        gWn_cur = FDOT2(w2n[4*k+2], H2(c4.z), gWn_cur);
        gWn_cur = FDOT2(w2n[4*k+3], H2(c4.w), gWn_cur);
      }
    }
    for (int c=0; c<256; c++) {
      int tgt = (c+2 <= 256) ? (c+2) : 256;
      SPIN(&flgB[i], tgt);
      float gWn_nxt = 0.f;
      if (c < 255) {
        const uint4* ap = (const uint4*)a16s[i][(c+1)&7];
        #pragma unroll
        for (int k=0;k<8;k++){ uint4 c4 = ap[k];
          gWn_nxt = FDOT2(w2n[4*k+0], H2(c4.x), gWn_nxt);
          gWn_nxt = FDOT2(w2n[4*k+1], H2(c4.y), gWn_nxt);
          gWn_nxt = FDOT2(w2n[4*k+2], H2(c4.z), gWn_nxt);
          gWn_nxt = FDOT2(w2n[4*k+3], H2(c4.w), gWn_nxt);
        }
      }
      float ghr = bhr, ghz = bhz, ghn = bhn;
      const uint4* hp = (const uint4*)h16s[i][(c+15)&15];
      #pragma unroll
      for (int k=0;k<8;k++){ uint4 c4 = hp[k];
        h2 p0=H2(c4.x), p1=H2(c4.y), p2=H2(c4.z), p3=H2(c4.w);
        ghr=FDOT2(wr[4*k+0],p0,ghr); ghr=FDOT2(wr[4*k+1],p1,ghr); ghr=FDOT2(wr[4*k+2],p2,ghr); ghr=FDOT2(wr[4*k+3],p3,ghr);
        ghz=FDOT2(wz[4*k+0],p0,ghz); ghz=FDOT2(wz[4*k+1],p1,ghz); ghz=FDOT2(wz[4*k+2],p2,ghz); ghz=FDOT2(wz[4*k+3],p3,ghz);
        ghn=FDOT2(wn[4*k+0],p0,ghn); ghn=FDOT2(wn[4*k+1],p1,ghn); ghn=FDOT2(wn[4*k+2],p2,ghn); ghn=FDOT2(wn[4*k+3],p3,ghn);
      }
      float gr  = gi3s[i][c&3][0][lane];
      float gzp = gi3s[i][c&3][1][lane];
      float gnp = gi3s[i][c&3][2][lane];
      float rg = 1.f/(1.f+__expf(-(gr+ghr)));
      float zg = 1.f/(1.f+__expf(-(gzp+ghz)));
      float xn = gnp + gWn_cur + rg*ghn;
      float e2 = __expf(2.f*xn);
      float ng = 1.f - 2.f/(e2+1.f);
      hreg = zg*hreg + (1.f-zg)*ng;
      if (i < 3) { SPIN(&flgB[i+1], c-15); }   // h16 slot reuse (depth 16)
      SPIN(&flgC[i], c-7);                     // h32 slot reuse (depth 8)
      h16s[i][c&15][lane] = F2H(hreg);
      h32s[i][c&7][lane]  = hreg;
      if (lane == 0) WGREL(&flgH[i], c+1);
      gWn_cur = gWn_nxt;
    }
  } else {
    // ---------------- B: gi precompute + row I/O for chain i ----------------
    h2 u0[32],u1[32],u2[32],u3[32],m2r[32],m2z[32];
    #pragma unroll
    for (int d=0; d<32; d++) {
      u0[d] = H2(U16[(lane)*32+d]);
      u1[d] = H2(U16[(64+lane)*32+d]);
      u2[d] = H2(U16[(128+lane)*32+d]);
      u3[d] = H2(U16[(192+lane)*32+d]);
      m2r[d]= H2(WM16[(lane)*32+d]);
      m2z[d]= H2(WM16[(64+lane)*32+d]);
    }
    const float cbr = cb[lane], cbz = cb[64+lane], cbn = cb[128+lane];
    const int qrow = q[b*64+t];
    const float xr = xe1[(b*64+t)*64+lane];
    const unsigned* hfp = hfu + (size_t)(b*65 + 4*tg)*16384;     // rows of t-1 (i==0, tg>0)
    unsigned* hfoU = hfu + (size_t)(b*65 + t + 1)*16384;
    float*    hfoF = h_full + (size_t)(b*65 + t + 1)*16384;
    unsigned* gfp = gflag + (b*16 + tg - 1);
    unsigned* gfc = gflag + (b*16 + tg);
    unsigned gv = 0;
    float e1cur = (qrow == 0) ? xr : qe1[lane];
    const unsigned short (*src)[64] = (i == 0) ? inbox : h16s[i-1];

    for (int s=0; s<256; s++) {
      SPIN(&flgH[i], s-3);   // gi3/a16 slot reuse
      if (i == 0) {
        unsigned short hv;
        if (tg == 0) {
          unsigned uu = I16[s*32 + (lane>>1)];
          hv = (lane&1) ? (unsigned short)(uu>>16) : (unsigned short)(uu&0xffff);
        } else {
          while (gv < (unsigned)(s+1)) {
            gv = __hip_atomic_load(gfp, __ATOMIC_RELAXED, __HIP_MEMORY_SCOPE_AGENT);
            if (gv < (unsigned)(s+1)) __builtin_amdgcn_s_sleep(2);
          }
          unsigned wv = __hip_atomic_load(&hfp[s*64+lane], __ATOMIC_RELAXED, __HIP_MEMORY_SCOPE_AGENT);
          union{unsigned u; float f;} cv; cv.u = wv;
          hv = F2H(cv.f);
        }
        inbox[s&15][lane] = hv;
        asm volatile("s_waitcnt lgkmcnt(0)" ::: "memory");
      } else {
        SPIN(&flgH[i-1], s+1);
      }
      float m1 = e1cur, gr = cbr, gz = cbz, gn = cbn;
      const uint4* rp = (const uint4*)src[s&15];
      #pragma unroll
      for (int k=0;k<8;k++){ uint4 c4 = rp[k];
        h2 p0=H2(c4.x), p1=H2(c4.y), p2=H2(c4.z), p3=H2(c4.w);
        m1=FDOT2(u0[4*k+0],p0,m1); m1=FDOT2(u0[4*k+1],p1,m1); m1=FDOT2(u0[4*k+2],p2,m1); m1=FDOT2(u0[4*k+3],p3,m1);
        gr=FDOT2(u1[4*k+0],p0,gr); gr=FDOT2(u1[4*k+1],p1,gr); gr=FDOT2(u1[4*k+2],p2,gr); gr=FDOT2(u1[4*k+3],p3,gr);
        gz=FDOT2(u2[4*k+0],p0,gz); gz=FDOT2(u2[4*k+1],p1,gz); gz=FDOT2(u2[4*k+2],p2,gz); gz=FDOT2(u2[4*k+3],p3,gz);
        gn=FDOT2(u3[4*k+0],p0,gn); gn=FDOT2(u3[4*k+1],p1,gn); gn=FDOT2(u3[4*k+2],p2,gn); gn=FDOT2(u3[4*k+3],p3,gn);
      }
      float av = fmaxf(m1, 0.f);
      a16s[i][s&7][lane] = F2H(av);
      asm volatile("s_waitcnt lgkmcnt(0)" ::: "memory");
      float g2r = 0.f, g2z = 0.f;
      {
        const uint4* ap = (const uint4*)a16s[i][s&7];
        #pragma unroll
        for (int k=0;k<8;k++){ uint4 c4 = ap[k];
          h2 p0=H2(c4.x), p1=H2(c4.y), p2=H2(c4.z), p3=H2(c4.w);
          g2r=FDOT2(m2r[4*k+0],p0,g2r); g2r=FDOT2(m2r[4*k+1],p1,g2r); g2r=FDOT2(m2r[4*k+2],p2,g2r); g2r=FDOT2(m2r[4*k+3],p3,g2r);
          g2z=FDOT2(m2z[4*k+0],p0,g2z); g2z=FDOT2(m2z[4*k+1],p1,g2z); g2z=FDOT2(m2z[4*k+2],p2,g2z); g2z=FDOT2(m2z[4*k+3],p3,g2z);
        }
      }
      gi3s[i][s&3][0][lane] = gr + g2r;
      gi3s[i][s&3][1][lane] = gz + g2z;
      gi3s[i][s&3][2][lane] = gn;
      if (lane == 0) WGREL(&flgB[i], s+1);
      if (s < 255) e1cur = ((s+1) == qrow) ? xr : qe1[(s+1)*64+lane];
      int cc = s-3;
      if (cc >= 0) {
        SPIN(&flgH[i], cc+1);
        float hv = h32s[i][cc&7][lane];
        if (i == 3) {
          union{float f; unsigned u;} cu; cu.f = hv;
          __hip_atomic_store(&hfoU[cc*64+lane], cu.u, __ATOMIC_RELAXED, __HIP_MEMORY_SCOPE_AGENT);
        } else {
          hfoF[cc*64+lane] = hv;
        }
        if (lane == 0) WGREL(&flgC[i], cc+1);
        if (i == 3 && (cc&3) == 3) {
          asm volatile("s_waitcnt vmcnt(0)" ::: "memory");
          if (lane == 0) __hip_atomic_store(gfc, (unsigned)(cc+1), __ATOMIC_RELAXED, __HIP_MEMORY_SCOPE_AGENT);
        }
      }
    }
    for (int cc=253; cc<256; cc++) {
      SPIN(&flgH[i], cc+1);
      float hv = h32s[i][cc&7][lane];
      if (i == 3) {
        union{float f; unsigned u;} cu; cu.f = hv;
        __hip_atomic_store(&hfoU[cc*64+lane], cu.u, __ATOMIC_RELAXED, __HIP_MEMORY_SCOPE_AGENT);
      } else {
        hfoF[cc*64+lane] = hv;
      }
      if (lane == 0) WGREL(&flgC[i], cc+1);
      if (i == 3 && (cc&3) == 3) {
        asm volatile("s_waitcnt vmcnt(0)" ::: "memory");
        if (lane == 0) __hip_atomic_store(gfc, (unsigned)(cc+1), __ATOMIC_RELAXED, __HIP_MEMORY_SCOPE_AGENT);
      }
    }
  }
}

// ================= hw[b][u][c] = h_full[b][u][c][:] . out_w =================
__global__ __launch_bounds__(256) void kHw(const float* __restrict__ h_full,
    const float* __restrict__ out_w, float* __restrict__ hw)
{
  __shared__ float ow[64];
  if (threadIdx.x < 64) ow[threadIdx.x] = out_w[threadIdx.x];
  __syncthreads();
  const int blk = blockIdx.x, c = threadIdx.x;
  const float* hp = h_full + ((size_t)blk*256 + c)*64;
  float s = 0.f;
  #pragma unroll
  for (int f=0; f<64; f++) s += hp[f]*ow[f];
  hw[blk*256+c] = s;
}

// ================= readout =================
__global__ __launch_bounds__(256) void kY(const int* __restrict__ q,
    const float* __restrict__ ws, const float* __restrict__ bias,
    const float* __restrict__ theta, float* __restrict__ y)
{
  const float* G  = ws + WS_G;
  const float* hw = ws + WS_HW;
  const int b = blockIdx.x >> 2, tq = blockIdx.x & 3;
  const int c = threadIdx.x;
  __shared__ float siml[64][256];
  for (int u=0; u<64; u++) {
    int qq = q[b*64+u];
    siml[u][c] = G[qq*256+c];
  }
  __syncthreads();
  const float rate = __expf(theta[0]);
  const float bv = bias[c];
  const float* hwb = hw + b*65*256;
  for (int tt=0; tt<16; tt++) {
    const int t = tq*16+tt;
    float mx = -1e30f;
    for (int u=0; u<=t; u++) {
      float s = __expf(-rate*(float)(t-u))*siml[u][c];
      mx = fmaxf(mx, s);
    }
    float se = 0.f, sw = 0.f;
    for (int u=0; u<=t; u++) {
      float s = __expf(-rate*(float)(t-u))*siml[u][c];
      float e = __expf(s-mx);
      se += e; sw += e*hwb[u*256+c];
    }
    float lg = hwb[(t+1)*256+c] + sw/se + bv;
    y[(b*64+t)*256+c] = 1.f/(1.f+__expf(-lg));
  }
}

extern "C" void kernel_launch(void* const* d_in, const int* in_sizes, int n_in,
                              void* d_out, int out_size, void* d_ws, size_t ws_size,
                              hipStream_t stream)
{
  (void)in_sizes; (void)n_in; (void)out_size; (void)ws_size;
  const int*   q      = (const int*)  d_in[0];
  const int*   r      = (const int*)  d_in[1];
  const float* x_emb  = (const float*)d_in[2];
  const float* q_emb  = (const float*)d_in[3];
  const float* init_h = (const float*)d_in[4];
  const float* w1     = (const float*)d_in[5];
  const float* b1     = (const float*)d_in[6];
  const float* w2     = (const float*)d_in[7];
  const float* b2     = (const float*)d_in[8];
  const float* w_ih   = (const float*)d_in[9];
  const float* w_hh   = (const float*)d_in[10];
  const float* b_ih   = (const float*)d_in[11];
  const float* b_hh   = (const float*)d_in[12];
  const float* bias   = (const float*)d_in[13];
  const float* out_w  = (const float*)d_in[14];
  const float* theta  = (const float*)d_in[15];

  float* out    = (float*)d_out;
  float* y      = out;
  float* h_full = out + 262144;
  float* ws     = (float*)d_ws;

  hipMemsetAsync((unsigned*)ws + WS_GFLAG, 0, 256*sizeof(unsigned), stream);
  kPrep<<<1713,256,0,stream>>>(q,r,x_emb,q_emb,init_h,w1,b1,w2,b2,w_ih,w_hh,b_ih,ws,h_full);
  {
    void* ka[] = { (void*)&q, (void*)&b_hh, (void*)&ws, (void*)&h_full };
    hipError_t e = hipLaunchCooperativeKernel((const void*)kA, dim3(256), dim3(512), ka, 0, stream);
    if (e != hipSuccess) {
      kA<<<dim3(256),dim3(512),0,stream>>>(q,b_hh,ws,h_full);
    }
  }
  kHw<<<1040,256,0,stream>>>(h_full, out_w, ws + WS_HW);
  kY<<<64,256,0,stream>>>(q, ws, bias, theta, y);
}